// Round 1
// baseline (3217.910 us; speedup 1.0000x reference)
//
#include <hip/hip_runtime.h>
#include <hip/hip_bf16.h>

typedef __attribute__((ext_vector_type(8))) short bfrag_t;   // 8 bf16 (4 VGPRs)
typedef __attribute__((ext_vector_type(4))) float accum_t;   // 4 f32

static_assert(sizeof(bfrag_t) == 16, "frag size");

static constexpr int M_NODES = 50000;
static constexpr int E_EDGES = 156000;
static constexpr int D       = 512;

// ---- manual RNE f32 -> bf16 (inputs finite; avoids header API variance) ----
__device__ __forceinline__ unsigned short f2bf(float f) {
  unsigned int u = __float_as_uint(f);
  u = (u + 0x7FFFu + ((u >> 16) & 1u)) >> 16;
  return (unsigned short)u;
}

__device__ __forceinline__ void gll16(const unsigned short* g, unsigned short* l) {
  __builtin_amdgcn_global_load_lds(
      (const __attribute__((address_space(1))) void*)g,
      (__attribute__((address_space(3))) void*)l,
      16, 0, 0);
}

// ---------------- weight cast + transpose: Wt[mat][n][k] = bf16(W[mat][k][n]) ----
__global__ void cast_w_kernel(const float* __restrict__ Wself,
                              const float* __restrict__ W1,
                              const float* __restrict__ W2,
                              unsigned short* __restrict__ Wt) {
  int idx = blockIdx.x * 256 + threadIdx.x;
  if (idx >= 7 * 262144) return;
  int mat = idx >> 18;
  int rem = idx & 262143;
  int k = rem >> 9;
  int n = rem & 511;
  float v;
  if (mat == 0)      v = Wself[rem];
  else if (mat <= 3) v = W1[(size_t)(mat - 1) * 262144 + rem];
  else               v = W2[(size_t)(mat - 4) * 262144 + rem];
  Wt[(size_t)mat * 262144 + (size_t)n * 512 + k] = f2bf(v);
}

// ---------------- zero fp32 buffer ----------------
__global__ void zero_kernel(float4* __restrict__ p, int n4) {
  int stride = gridDim.x * blockDim.x;
  for (int i = blockIdx.x * blockDim.x + threadIdx.x; i < n4; i += stride)
    p[i] = make_float4(0.f, 0.f, 0.f, 0.f);
}

// ---------------- h = bf16(x [+ agg]) ----------------
template <bool USE_AGG>
__global__ void build_h_kernel(const float* __restrict__ x,
                               const float* __restrict__ agg,
                               unsigned short* __restrict__ h, int n) {
  int stride = gridDim.x * blockDim.x;
  int n4 = n >> 2;
  for (int i = blockIdx.x * blockDim.x + threadIdx.x; i < n4; i += stride) {
    float4 v = ((const float4*)x)[i];
    if (USE_AGG) {
      float4 a = ((const float4*)agg)[i];
      v.x += a.x; v.y += a.y; v.z += a.z; v.w += a.w;
    }
    ushort4 u;
    u.x = f2bf(v.x); u.y = f2bf(v.y); u.z = f2bf(v.z); u.w = f2bf(v.w);
    ((ushort4*)h)[i] = u;
  }
}

// ---------------- scatter: agg[dst] += x[src] for edges of type rel ----------
__global__ void scatter_kernel(const float* __restrict__ x,
                               const int* __restrict__ ei,
                               const int* __restrict__ et,
                               int rel, float* __restrict__ agg) {
  int e    = (int)((blockIdx.x * (unsigned)blockDim.x + threadIdx.x) >> 6);
  int lane = threadIdx.x & 63;
  if (e >= E_EDGES) return;
  if (et[e] != rel) return;
  int src = ei[e];
  int dst = ei[E_EDGES + e];
  const float4* xs = (const float4*)(x + (size_t)src * D);
  float* ad = agg + (size_t)dst * D;
  float4 v0 = xs[lane * 2];
  float4 v1 = xs[lane * 2 + 1];
  int c = lane * 8;
  unsafeAtomicAdd(ad + c + 0, v0.x);
  unsafeAtomicAdd(ad + c + 1, v0.y);
  unsafeAtomicAdd(ad + c + 2, v0.z);
  unsafeAtomicAdd(ad + c + 3, v0.w);
  unsafeAtomicAdd(ad + c + 4, v1.x);
  unsafeAtomicAdd(ad + c + 5, v1.y);
  unsafeAtomicAdd(ad + c + 6, v1.z);
  unsafeAtomicAdd(ad + c + 7, v1.w);
}

// ---------------- GEMM: C[M,512] = A[M,512](bf16) @ B[512,512] + bias --------
// Bt is B transposed [n][k] bf16. MODE 0: f32 store. 1: relu -> bf16 store.
// 2: f32 read-modify-write accumulate.
template <int MODE>
__global__ __launch_bounds__(256) void gemm_kernel(
    const unsigned short* __restrict__ A,
    const unsigned short* __restrict__ Bt,
    const float* __restrict__ bias,
    float* __restrict__ outF,
    unsigned short* __restrict__ outB) {
  __shared__ alignas(16) unsigned short As[4096];  // [kc][row][8]
  __shared__ alignas(16) unsigned short Bs[4096];  // [kc][ncol][8]
  const int tid  = threadIdx.x;
  const int lane = tid & 63;
  const int wid  = tid >> 6;
  const int wr   = wid >> 1;
  const int wc   = wid & 1;
  const int tileM = blockIdx.y * 128;
  const int tileN = blockIdx.x * 128;

  accum_t acc[4][4] = {};

  // staging: t in {tid, tid+256}; LDS linear offset t*16B; kc = t>>7, row = t&127
  const int t0 = tid, t1 = tid + 256;
  const int kc0 = t0 >> 7, r0 = t0 & 127;
  const int kc1 = t1 >> 7, r1 = t1 & 127;
  int ar0 = tileM + r0; ar0 = ar0 < M_NODES ? ar0 : M_NODES - 1;
  int ar1 = tileM + r1; ar1 = ar1 < M_NODES ? ar1 : M_NODES - 1;
  const unsigned short* gA0 = A + (size_t)ar0 * D + kc0 * 8;
  const unsigned short* gA1 = A + (size_t)ar1 * D + kc1 * 8;
  const unsigned short* gB0 = Bt + (size_t)(tileN + r0) * D + kc0 * 8;
  const unsigned short* gB1 = Bt + (size_t)(tileN + r1) * D + kc1 * 8;
  unsigned short* lA0 = &As[t0 * 8];
  unsigned short* lA1 = &As[t1 * 8];
  unsigned short* lB0 = &Bs[t0 * 8];
  unsigned short* lB1 = &Bs[t1 * 8];

  const int kcl = lane >> 4;   // which 8-wide k-chunk this lane supplies
  const int fr  = lane & 15;   // row (A) / col (B) within 16x16 fragment
  const unsigned short* pAf = &As[kcl * 1024 + (wr * 64 + fr) * 8];
  const unsigned short* pBf = &Bs[kcl * 1024 + (wc * 64 + fr) * 8];

  for (int ks = 0; ks < 16; ++ks) {
    const int koff = ks * 32;
    gll16(gA0 + koff, lA0);
    gll16(gA1 + koff, lA1);
    gll16(gB0 + koff, lB0);
    gll16(gB1 + koff, lB1);
    __syncthreads();
    bfrag_t a[4], b[4];
#pragma unroll
    for (int m = 0; m < 4; ++m) a[m] = *(const bfrag_t*)(pAf + m * 16 * 8);
#pragma unroll
    for (int n = 0; n < 4; ++n) b[n] = *(const bfrag_t*)(pBf + n * 16 * 8);
#pragma unroll
    for (int m = 0; m < 4; ++m)
#pragma unroll
      for (int n = 0; n < 4; ++n)
        acc[m][n] = __builtin_amdgcn_mfma_f32_16x16x32_bf16(a[m], b[n], acc[m][n], 0, 0, 0);
    __syncthreads();
  }

  // epilogue: C row = (lane>>4)*4 + reg, col = lane&15 (m89-verified layout)
  const int rq = lane >> 4;
#pragma unroll
  for (int n = 0; n < 4; ++n) {
    const int col = tileN + wc * 64 + n * 16 + fr;
    const float bv = bias[col];
#pragma unroll
    for (int m = 0; m < 4; ++m) {
      const int rbase = tileM + wr * 64 + m * 16 + rq * 4;
#pragma unroll
      for (int q = 0; q < 4; ++q) {
        const int row = rbase + q;
        if (row < M_NODES) {
          float v = acc[m][n][q] + bv;
          const size_t idx = (size_t)row * D + col;
          if (MODE == 0)      outF[idx] = v;
          else if (MODE == 1) outB[idx] = f2bf(fmaxf(v, 0.f));
          else                outF[idx] += v;
        }
      }
    }
  }
}

extern "C" void kernel_launch(void* const* d_in, const int* in_sizes, int n_in,
                              void* d_out, int out_size, void* d_ws, size_t ws_size,
                              hipStream_t stream) {
  const float* x     = (const float*)d_in[0];
  const int*   ei    = (const int*)d_in[1];
  const int*   et    = (const int*)d_in[2];
  const float* Wself = (const float*)d_in[3];
  const float* bself = (const float*)d_in[4];
  const float* W1    = (const float*)d_in[5];
  const float* b1    = (const float*)d_in[6];
  const float* W2    = (const float*)d_in[7];
  const float* b2    = (const float*)d_in[8];
  float* out = (float*)d_out;

  char* ws = (char*)d_ws;
  unsigned short* h   = (unsigned short*)ws;               // 51.2 MB  bf16 A operand
  float*          agg = (float*)(ws + 51200000);           // 102.4 MB fp32 segment-sum
  unsigned short* mid = (unsigned short*)(ws + 51200000);  // aliases agg (51.2 MB bf16)
  unsigned short* Wt  = (unsigned short*)(ws + 153600000); // 3.67 MB  bf16 W^T x7

  dim3 gemm_grid(4, (M_NODES + 127) / 128);  // x = N-tile (fast) -> A-tile L2 reuse

  cast_w_kernel<<<7 * 1024, 256, 0, stream>>>(Wself, W1, W2, Wt);
  build_h_kernel<false><<<2048, 256, 0, stream>>>(x, nullptr, h, M_NODES * D);
  gemm_kernel<0><<<gemm_grid, 256, 0, stream>>>(h, Wt, bself, out, nullptr);

  for (int r = 0; r < 3; ++r) {
    zero_kernel<<<2048, 256, 0, stream>>>((float4*)agg, M_NODES * D / 4);
    scatter_kernel<<<E_EDGES / 4, 256, 0, stream>>>(x, ei, et, r, agg);
    build_h_kernel<true><<<2048, 256, 0, stream>>>(x, agg, h, M_NODES * D);
    gemm_kernel<1><<<gemm_grid, 256, 0, stream>>>(h, Wt + (size_t)(1 + r) * 262144,
                                                  b1 + (size_t)r * 512, nullptr, mid);
    gemm_kernel<2><<<gemm_grid, 256, 0, stream>>>(mid, Wt + (size_t)(4 + r) * 262144,
                                                  b2 + (size_t)r * 512, out, nullptr);
  }
}

// Round 2
// 1317.292 us; speedup vs baseline: 2.4428x; 2.4428x over previous
//
#include <hip/hip_runtime.h>
#include <hip/hip_bf16.h>

typedef __attribute__((ext_vector_type(8))) short bfrag_t;   // 8 bf16 (4 VGPRs)
typedef __attribute__((ext_vector_type(4))) float accum_t;   // 4 f32

static_assert(sizeof(bfrag_t) == 16, "frag size");

static constexpr int M_NODES = 50000;
static constexpr int E_EDGES = 156000;
static constexpr int D       = 512;

// ---- manual RNE f32 -> bf16 ----
__device__ __forceinline__ unsigned short f2bf(float f) {
  unsigned int u = __float_as_uint(f);
  u = (u + 0x7FFFu + ((u >> 16) & 1u)) >> 16;
  return (unsigned short)u;
}

__device__ __forceinline__ void gll16(const unsigned short* g, unsigned short* l) {
  __builtin_amdgcn_global_load_lds(
      (const __attribute__((address_space(1))) void*)g,
      (__attribute__((address_space(3))) void*)l,
      16, 0, 0);
}

// ---------------- weight cast + transpose: Wt[mat][n][k] = bf16(W[mat][k][n]) ----
__global__ void cast_w_kernel(const float* __restrict__ Wself,
                              const float* __restrict__ W1,
                              const float* __restrict__ W2,
                              unsigned short* __restrict__ Wt) {
  int idx = blockIdx.x * 256 + threadIdx.x;
  if (idx >= 7 * 262144) return;
  int mat = idx >> 18;
  int rem = idx & 262143;
  int k = rem >> 9;
  int n = rem & 511;
  float v;
  if (mat == 0)      v = Wself[rem];
  else if (mat <= 3) v = W1[(size_t)(mat - 1) * 262144 + rem];
  else               v = W2[(size_t)(mat - 4) * 262144 + rem];
  Wt[(size_t)mat * 262144 + (size_t)n * 512 + k] = f2bf(v);
}

// ---------------- h = bf16(x [+ agg]) ----------------
template <bool USE_AGG>
__global__ void build_h_kernel(const float* __restrict__ x,
                               const float* __restrict__ agg,
                               unsigned short* __restrict__ h, int n) {
  int stride = gridDim.x * blockDim.x;
  int n4 = n >> 2;
  for (int i = blockIdx.x * blockDim.x + threadIdx.x; i < n4; i += stride) {
    float4 v = ((const float4*)x)[i];
    if (USE_AGG) {
      float4 a = ((const float4*)agg)[i];
      v.x += a.x; v.y += a.y; v.z += a.z; v.w += a.w;
    }
    ushort4 u;
    u.x = f2bf(v.x); u.y = f2bf(v.y); u.z = f2bf(v.z); u.w = f2bf(v.w);
    ((ushort4*)h)[i] = u;
  }
}

// ---------------- scatter: agg[dst] += x[src] for edges of type rel ----------
// Coalesced mapping: atomic instruction j covers agg row bytes [j*256, j*256+256)
// across the 64 lanes -> TCC merges into full sectors (fixes 8x write amp).
__global__ void scatter_kernel(const float* __restrict__ x,
                               const int* __restrict__ ei,
                               const int* __restrict__ et,
                               int rel, float* __restrict__ agg) {
  int e    = blockIdx.x * 4 + (threadIdx.x >> 6);
  int lane = threadIdx.x & 63;
  if (e >= E_EDGES) return;
  if (et[e] != rel) return;
  int src = ei[e];
  int dst = ei[E_EDGES + e];
  const float* xs = x + (size_t)src * D;
  float* ad = agg + (size_t)dst * D;
  float v[8];
#pragma unroll
  for (int j = 0; j < 8; ++j) v[j] = xs[j * 64 + lane];
#pragma unroll
  for (int j = 0; j < 8; ++j) unsafeAtomicAdd(ad + j * 64 + lane, v[j]);
}

// ---------------- GEMM: C[M,512] = A[M,512](bf16) @ B[512,512] + bias --------
// Bt is B transposed [n][k] bf16. MODE 0: f32 store. 1: relu -> bf16 store.
// 2: f32 read-modify-write accumulate.
template <int MODE>
__global__ __launch_bounds__(256) void gemm_kernel(
    const unsigned short* __restrict__ A,
    const unsigned short* __restrict__ Bt,
    const float* __restrict__ bias,
    float* __restrict__ outF,
    unsigned short* __restrict__ outB) {
  __shared__ alignas(16) unsigned short As[4096];  // [kc][row][8]
  __shared__ alignas(16) unsigned short Bs[4096];  // [kc][ncol][8]
  const int tid  = threadIdx.x;
  const int lane = tid & 63;
  const int wid  = tid >> 6;
  const int wr   = wid >> 1;
  const int wc   = wid & 1;
  const int tileM = blockIdx.y * 128;
  const int tileN = blockIdx.x * 128;

  accum_t acc[4][4] = {};

  const int t0 = tid, t1 = tid + 256;
  const int kc0 = t0 >> 7, r0 = t0 & 127;
  const int kc1 = t1 >> 7, r1 = t1 & 127;
  int ar0 = tileM + r0; ar0 = ar0 < M_NODES ? ar0 : M_NODES - 1;
  int ar1 = tileM + r1; ar1 = ar1 < M_NODES ? ar1 : M_NODES - 1;
  const unsigned short* gA0 = A + (size_t)ar0 * D + kc0 * 8;
  const unsigned short* gA1 = A + (size_t)ar1 * D + kc1 * 8;
  const unsigned short* gB0 = Bt + (size_t)(tileN + r0) * D + kc0 * 8;
  const unsigned short* gB1 = Bt + (size_t)(tileN + r1) * D + kc1 * 8;
  unsigned short* lA0 = &As[t0 * 8];
  unsigned short* lA1 = &As[t1 * 8];
  unsigned short* lB0 = &Bs[t0 * 8];
  unsigned short* lB1 = &Bs[t1 * 8];

  const int kcl = lane >> 4;
  const int fr  = lane & 15;
  const unsigned short* pAf = &As[kcl * 1024 + (wr * 64 + fr) * 8];
  const unsigned short* pBf = &Bs[kcl * 1024 + (wc * 64 + fr) * 8];

  for (int ks = 0; ks < 16; ++ks) {
    const int koff = ks * 32;
    gll16(gA0 + koff, lA0);
    gll16(gA1 + koff, lA1);
    gll16(gB0 + koff, lB0);
    gll16(gB1 + koff, lB1);
    __syncthreads();
    bfrag_t a[4], b[4];
#pragma unroll
    for (int m = 0; m < 4; ++m) a[m] = *(const bfrag_t*)(pAf + m * 16 * 8);
#pragma unroll
    for (int n = 0; n < 4; ++n) b[n] = *(const bfrag_t*)(pBf + n * 16 * 8);
#pragma unroll
    for (int m = 0; m < 4; ++m)
#pragma unroll
      for (int n = 0; n < 4; ++n)
        acc[m][n] = __builtin_amdgcn_mfma_f32_16x16x32_bf16(a[m], b[n], acc[m][n], 0, 0, 0);
    __syncthreads();
  }

  const int rq = lane >> 4;
#pragma unroll
  for (int n = 0; n < 4; ++n) {
    const int col = tileN + wc * 64 + n * 16 + fr;
    const float bv = bias[col];
#pragma unroll
    for (int m = 0; m < 4; ++m) {
      const int rbase = tileM + wr * 64 + m * 16 + rq * 4;
#pragma unroll
      for (int q = 0; q < 4; ++q) {
        const int row = rbase + q;
        if (row < M_NODES) {
          float v = acc[m][n][q] + bv;
          const size_t idx = (size_t)row * D + col;
          if (MODE == 0)      outF[idx] = v;
          else if (MODE == 1) outB[idx] = f2bf(fmaxf(v, 0.f));
          else                outF[idx] += v;
        }
      }
    }
  }
}

extern "C" void kernel_launch(void* const* d_in, const int* in_sizes, int n_in,
                              void* d_out, int out_size, void* d_ws, size_t ws_size,
                              hipStream_t stream) {
  const float* x     = (const float*)d_in[0];
  const int*   ei    = (const int*)d_in[1];
  const int*   et    = (const int*)d_in[2];
  const float* Wself = (const float*)d_in[3];
  const float* bself = (const float*)d_in[4];
  const float* W1    = (const float*)d_in[5];
  const float* b1    = (const float*)d_in[6];
  const float* W2    = (const float*)d_in[7];
  const float* b2    = (const float*)d_in[8];
  float* out = (float*)d_out;

  char* ws = (char*)d_ws;
  unsigned short* h   = (unsigned short*)ws;               // 51.2 MB  bf16 A operand
  float*          agg = (float*)(ws + 51200000);           // 102.4 MB fp32 segment-sum
  unsigned short* mid = (unsigned short*)(ws + 51200000);  // aliases agg (51.2 MB bf16)
  unsigned short* Wt  = (unsigned short*)(ws + 153600000); // 3.67 MB  bf16 W^T x7

  dim3 gemm_grid(4, (M_NODES + 127) / 128);  // x = N-tile (fast) -> A-tile L2 reuse

  cast_w_kernel<<<7 * 1024, 256, 0, stream>>>(Wself, W1, W2, Wt);
  build_h_kernel<false><<<2048, 256, 0, stream>>>(x, nullptr, h, M_NODES * D);
  gemm_kernel<0><<<gemm_grid, 256, 0, stream>>>(h, Wt, bself, out, nullptr);

  for (int r = 0; r < 3; ++r) {
    hipMemsetAsync(agg, 0, (size_t)M_NODES * D * sizeof(float), stream);
    scatter_kernel<<<(E_EDGES + 3) / 4, 256, 0, stream>>>(x, ei, et, r, agg);
    build_h_kernel<true><<<2048, 256, 0, stream>>>(x, agg, h, M_NODES * D);
    gemm_kernel<1><<<gemm_grid, 256, 0, stream>>>(h, Wt + (size_t)(1 + r) * 262144,
                                                  b1 + (size_t)r * 512, nullptr, mid);
    gemm_kernel<2><<<gemm_grid, 256, 0, stream>>>(mid, Wt + (size_t)(4 + r) * 262144,
                                                  b2 + (size_t)r * 512, out, nullptr);
  }
}

// Round 3
// 1303.411 us; speedup vs baseline: 2.4688x; 1.0106x over previous
//
#include <hip/hip_runtime.h>
#include <hip/hip_bf16.h>

typedef __attribute__((ext_vector_type(8))) short bfrag_t;   // 8 bf16 (4 VGPRs)
typedef __attribute__((ext_vector_type(4))) float accum_t;   // 4 f32

static_assert(sizeof(bfrag_t) == 16, "frag size");

static constexpr int M_NODES = 50000;
static constexpr int E_EDGES = 156000;
static constexpr int D       = 512;
static constexpr int MT      = (M_NODES + 127) / 128;  // 391 M-tiles
static constexpr int NT      = 4;                      // 512/128 N-tiles
static constexpr int NWG     = MT * NT;                // 1564
static constexpr int XQ      = NWG / 8;                // 195
static constexpr int XR      = NWG % 8;                // 4

// ---- manual RNE f32 -> bf16 ----
__device__ __forceinline__ unsigned short f2bf(float f) {
  unsigned int u = __float_as_uint(f);
  u = (u + 0x7FFFu + ((u >> 16) & 1u)) >> 16;
  return (unsigned short)u;
}

__device__ __forceinline__ void gll16(const unsigned short* g, unsigned short* l) {
  __builtin_amdgcn_global_load_lds(
      (const __attribute__((address_space(1))) void*)g,
      (__attribute__((address_space(3))) void*)l,
      16, 0, 0);
}

// ---------------- weight cast + transpose: Wt[mat][n][k] = bf16(W[mat][k][n]) ----
__global__ void cast_w_kernel(const float* __restrict__ Wself,
                              const float* __restrict__ W1,
                              const float* __restrict__ W2,
                              unsigned short* __restrict__ Wt) {
  int idx = blockIdx.x * 256 + threadIdx.x;
  if (idx >= 7 * 262144) return;
  int mat = idx >> 18;
  int rem = idx & 262143;
  int k = rem >> 9;
  int n = rem & 511;
  float v;
  if (mat == 0)      v = Wself[rem];
  else if (mat <= 3) v = W1[(size_t)(mat - 1) * 262144 + rem];
  else               v = W2[(size_t)(mat - 4) * 262144 + rem];
  Wt[(size_t)mat * 262144 + (size_t)n * 512 + k] = f2bf(v);
}

// ---------------- h = bf16(x [+ agg]) ----------------
template <bool USE_AGG>
__global__ void build_h_kernel(const float* __restrict__ x,
                               const float* __restrict__ agg,
                               unsigned short* __restrict__ h, int n) {
  int stride = gridDim.x * blockDim.x;
  int n4 = n >> 2;
  for (int i = blockIdx.x * blockDim.x + threadIdx.x; i < n4; i += stride) {
    float4 v = ((const float4*)x)[i];
    if (USE_AGG) {
      float4 a = ((const float4*)agg)[i];
      v.x += a.x; v.y += a.y; v.z += a.z; v.w += a.w;
    }
    ushort4 u;
    u.x = f2bf(v.x); u.y = f2bf(v.y); u.z = f2bf(v.z); u.w = f2bf(v.w);
    ((ushort4*)h)[i] = u;
  }
}

// ---------------- scatter: agg[dst] += x[src] for edges of type rel ----------
__global__ void scatter_kernel(const float* __restrict__ x,
                               const int* __restrict__ ei,
                               const int* __restrict__ et,
                               int rel, float* __restrict__ agg) {
  int e    = blockIdx.x * 4 + (threadIdx.x >> 6);
  int lane = threadIdx.x & 63;
  if (e >= E_EDGES) return;
  if (et[e] != rel) return;
  int src = ei[e];
  int dst = ei[E_EDGES + e];
  const float* xs = x + (size_t)src * D;
  float* ad = agg + (size_t)dst * D;
  float v[8];
#pragma unroll
  for (int j = 0; j < 8; ++j) v[j] = xs[j * 64 + lane];
#pragma unroll
  for (int j = 0; j < 8; ++j) unsafeAtomicAdd(ad + j * 64 + lane, v[j]);
}

// ---------------- GEMM: C[M,512] = A[M,512](bf16) @ B[512,512] + bias --------
// Double-buffered LDS, counted-vmcnt prefetch (T3-min), XCD-chunked swizzle (T1).
// MODE 0: f32 store. 1: relu -> bf16 store. 2: f32 read-modify-write accumulate.
template <int MODE>
__global__ __launch_bounds__(256) void gemm_kernel(
    const unsigned short* __restrict__ A,
    const unsigned short* __restrict__ Bt,
    const float* __restrict__ bias,
    float* __restrict__ outF,
    unsigned short* __restrict__ outB) {
  __shared__ alignas(16) unsigned short As[2][4096];  // [buf][kc][row][8]
  __shared__ alignas(16) unsigned short Bs[2][4096];
  const int tid  = threadIdx.x;
  const int lane = tid & 63;
  const int wid  = tid >> 6;
  const int wr   = wid >> 1;
  const int wc   = wid & 1;

  // T1: bijective XCD-chunked swizzle (m204). Consecutive swz ids share an
  // A-tile (x fast) and land on one XCD -> A fetched once per 4 N-blocks.
  const int orig = blockIdx.x;
  const int xcd  = orig & 7;
  const int lid  = orig >> 3;
  const int swz  = (xcd < XR ? xcd * (XQ + 1) : XR * (XQ + 1) + (xcd - XR) * XQ) + lid;
  const int tileM = (swz >> 2) * 128;
  const int tileN = (swz & 3) * 128;

  accum_t acc[4][4] = {};

  const int t0 = tid, t1 = tid + 256;
  const int kc0 = t0 >> 7, r0 = t0 & 127;
  const int kc1 = t1 >> 7, r1 = t1 & 127;
  int ar0 = tileM + r0; ar0 = ar0 < M_NODES ? ar0 : M_NODES - 1;
  int ar1 = tileM + r1; ar1 = ar1 < M_NODES ? ar1 : M_NODES - 1;
  const unsigned short* gA0 = A + (size_t)ar0 * D + kc0 * 8;
  const unsigned short* gA1 = A + (size_t)ar1 * D + kc1 * 8;
  const unsigned short* gB0 = Bt + (size_t)(tileN + r0) * D + kc0 * 8;
  const unsigned short* gB1 = Bt + (size_t)(tileN + r1) * D + kc1 * 8;

  const int kcl = lane >> 4;
  const int fr  = lane & 15;
  const unsigned short* pAf = &As[0][kcl * 1024 + (wr * 64 + fr) * 8];
  const unsigned short* pBf = &Bs[0][kcl * 1024 + (wc * 64 + fr) * 8];

#define STAGE(b, ks)                                  \
  do {                                                \
    const int koff_ = (ks) * 32;                      \
    gll16(gA0 + koff_, &As[(b)][t0 * 8]);             \
    gll16(gA1 + koff_, &As[(b)][t1 * 8]);             \
    gll16(gB0 + koff_, &Bs[(b)][t0 * 8]);             \
    gll16(gB1 + koff_, &Bs[(b)][t1 * 8]);             \
  } while (0)

  STAGE(0, 0);
  for (int ks = 0; ks < 16; ++ks) {
    const int cur = ks & 1;
    if (ks < 15) {
      STAGE(cur ^ 1, ks + 1);                           // prefetch next tile
      asm volatile("s_waitcnt vmcnt(4)" ::: "memory");  // wait current only
    } else {
      asm volatile("s_waitcnt vmcnt(0)" ::: "memory");
    }
    __builtin_amdgcn_s_barrier();   // current tile visible to all waves

    bfrag_t a[4], b[4];
    const unsigned short* pA = pAf + cur * 4096;
    const unsigned short* pB = pBf + cur * 4096;
#pragma unroll
    for (int m = 0; m < 4; ++m) a[m] = *(const bfrag_t*)(pA + m * 16 * 8);
#pragma unroll
    for (int n = 0; n < 4; ++n) b[n] = *(const bfrag_t*)(pB + n * 16 * 8);
    __builtin_amdgcn_s_setprio(1);
#pragma unroll
    for (int m = 0; m < 4; ++m)
#pragma unroll
      for (int n = 0; n < 4; ++n)
        acc[m][n] = __builtin_amdgcn_mfma_f32_16x16x32_bf16(a[m], b[n], acc[m][n], 0, 0, 0);
    __builtin_amdgcn_s_setprio(0);
    __builtin_amdgcn_s_barrier();   // all waves done reading buf[cur]
  }
#undef STAGE

  const int rq = lane >> 4;
#pragma unroll
  for (int n = 0; n < 4; ++n) {
    const int col = tileN + wc * 64 + n * 16 + fr;
    const float bv = bias[col];
#pragma unroll
    for (int m = 0; m < 4; ++m) {
      const int rbase = tileM + wr * 64 + m * 16 + rq * 4;
#pragma unroll
      for (int q = 0; q < 4; ++q) {
        const int row = rbase + q;
        if (row < M_NODES) {
          float v = acc[m][n][q] + bv;
          const size_t idx = (size_t)row * D + col;
          if (MODE == 0)      outF[idx] = v;
          else if (MODE == 1) outB[idx] = f2bf(fmaxf(v, 0.f));
          else                outF[idx] += v;
        }
      }
    }
  }
}

extern "C" void kernel_launch(void* const* d_in, const int* in_sizes, int n_in,
                              void* d_out, int out_size, void* d_ws, size_t ws_size,
                              hipStream_t stream) {
  const float* x     = (const float*)d_in[0];
  const int*   ei    = (const int*)d_in[1];
  const int*   et    = (const int*)d_in[2];
  const float* Wself = (const float*)d_in[3];
  const float* bself = (const float*)d_in[4];
  const float* W1    = (const float*)d_in[5];
  const float* b1    = (const float*)d_in[6];
  const float* W2    = (const float*)d_in[7];
  const float* b2    = (const float*)d_in[8];
  float* out = (float*)d_out;

  char* ws = (char*)d_ws;
  unsigned short* h   = (unsigned short*)ws;               // 51.2 MB  bf16 A operand
  float*          agg = (float*)(ws + 51200000);           // 102.4 MB fp32 segment-sum
  unsigned short* mid = (unsigned short*)(ws + 51200000);  // aliases agg (51.2 MB bf16)
  unsigned short* Wt  = (unsigned short*)(ws + 153600000); // 3.67 MB  bf16 W^T x7

  cast_w_kernel<<<7 * 1024, 256, 0, stream>>>(Wself, W1, W2, Wt);
  build_h_kernel<false><<<2048, 256, 0, stream>>>(x, nullptr, h, M_NODES * D);
  gemm_kernel<0><<<NWG, 256, 0, stream>>>(h, Wt, bself, out, nullptr);

  for (int r = 0; r < 3; ++r) {
    hipMemsetAsync(agg, 0, (size_t)M_NODES * D * sizeof(float), stream);
    scatter_kernel<<<(E_EDGES + 3) / 4, 256, 0, stream>>>(x, ei, et, r, agg);
    build_h_kernel<true><<<2048, 256, 0, stream>>>(x, agg, h, M_NODES * D);
    gemm_kernel<1><<<NWG, 256, 0, stream>>>(h, Wt + (size_t)(1 + r) * 262144,
                                            b1 + (size_t)r * 512, nullptr, mid);
    gemm_kernel<2><<<NWG, 256, 0, stream>>>(mid, Wt + (size_t)(4 + r) * 262144,
                                            b2 + (size_t)r * 512, out, nullptr);
  }
}